// Round 7
// baseline (87.888 us; speedup 1.0000x reference)
//
#include <hip/hip_runtime.h>

#define NT   24
#define CIN  9
#define NF   32
#define KM   16
#define HID  128
#define NCLS 10
#define SEQ_LEN (NT*CIN)   // 216
#define PADJ 12            // seq LDS row pitch (floats), 16B-aligned columns
#define NSTRIP 8           // 8 strips of 2 rows; pipelined via shfl
#define RSTRIP 2

// D[m-1,n-1] (forward DTW) == backtracked path-cost sum (telescoping).
// Cost via quadratic expansion ||k-x||^2 = ||k||^2 + ||x||^2 - 2 k.x with
// kf pre-scaled by -2: per cell = 1 add + 9 fma.
//
// Thread layout: block = 256 threads = 4 waves, 1 sequence per block.
// lane = strip*8 + f_lo (strip = lane>>3, 8 strips per wave);
// filter f = wave*8 + f_lo. Strip s computes rows [2s, 2s+2), skewed:
// step t works column j = t - s. Boundary D (row 2s+1) flows strip
// s -> s+1 via __shfl_up(.,8); value shuffled at step t (column t-s) is
// consumed at t+1 as 'up' and at t+2 as 'diag'.
__global__ __launch_bounds__(256, 8) void dtwnet_fused(
    const float* __restrict__ x,
    const float* __restrict__ kern,
    const float* __restrict__ W1, const float* __restrict__ b1,
    const float* __restrict__ W2, const float* __restrict__ b2,
    const float* __restrict__ Wl, const float* __restrict__ bl,
    float* __restrict__ out)
{
  __shared__ float seq_lds[NT*PADJ];
  __shared__ float bcol[NT];          // ||x_j||^2 per column
  __shared__ float feat_lds[NF];
  __shared__ float h1_lds[HID];
  __shared__ float h2_lds[HID];
  __shared__ float logit_lds[NCLS];

  const int tid  = threadIdx.x;
  const int bid  = blockIdx.x;
  const int wave = tid >> 6;
  const int lane = tid & 63;
  const int s    = lane >> 3;       // strip 0..7
  const int f_lo = lane & 7;
  const int f    = wave*8 + f_lo;   // filter 0..31

  // filter strip (2 rows x 9 ch = 18 floats, 8B-aligned) from global
  // (18 KB total, L2-hot), issued before the barrier.
  float kf[RSTRIP*CIN];
  {
    const float2* kp = (const float2*)(kern + f*(KM*CIN) + s*(RSTRIP*CIN));
    float2 t0=kp[0], t1=kp[1], t2=kp[2], t3=kp[3], t4=kp[4],
           t5=kp[5], t6=kp[6], t7=kp[7], t8=kp[8];
    kf[0]=t0.x; kf[1]=t0.y; kf[2]=t1.x; kf[3]=t1.y;
    kf[4]=t2.x; kf[5]=t2.y; kf[6]=t3.x; kf[7]=t3.y;
    kf[8]=t4.x; kf[9]=t4.y; kf[10]=t5.x; kf[11]=t5.y;
    kf[12]=t6.x; kf[13]=t6.y; kf[14]=t7.x; kf[15]=t7.y;
    kf[16]=t8.x; kf[17]=t8.y;
  }

  // stage this block's sequence (216 floats), padded to 12/timestep
  for (int d = tid; d < SEQ_LEN; d += 256) {
    int jj = d / CIN, cc = d - jj*CIN;
    seq_lds[jj*PADJ + cc] = x[bid*SEQ_LEN + d];
  }
  __syncthreads();

  // column norms ||x_j||^2
  if (tid < NT) {
    const float4* sp = (const float4*)(seq_lds + tid*PADJ);
    float4 q0 = sp[0], q1 = sp[1], q2 = sp[2];
    bcol[tid] = q0.x*q0.x + q0.y*q0.y + q0.z*q0.z + q0.w*q0.w
              + q1.x*q1.x + q1.y*q1.y + q1.z*q1.z + q1.w*q1.w
              + q2.x*q2.x;
  }

  // a[r] = ||k_r||^2, then pre-scale kf by -2
  float arow[RSTRIP];
  #pragma unroll
  for (int r = 0; r < RSTRIP; ++r) {
    float a = 0.f;
    #pragma unroll
    for (int c = 0; c < CIN; ++c) a = fmaf(kf[r*CIN+c], kf[r*CIN+c], a);
    arow[r] = a;
  }
  #pragma unroll
  for (int q = 0; q < RSTRIP*CIN; ++q) kf[q] *= -2.f;
  __syncthreads();

  float rowD[RSTRIP];
  float bndUp = 0.f, bndDg = 0.f;

  #pragma unroll 1
  for (int t = 0; t < NT + NSTRIP - 1; ++t) {   // 31 steps
    int j = t - s;
    bool active = (j >= 0) && (j < NT);
    float nb = 0.f;
    if (active) {
      const float4* sp = (const float4*)(seq_lds + j*PADJ);
      float4 q0 = sp[0], q1 = sp[1], q2 = sp[2];
      float bj = bcol[j];
      float sv[CIN] = {q0.x,q0.y,q0.z,q0.w,q1.x,q1.y,q1.z,q1.w,q2.x};
      float c0 = arow[0] + bj, c1 = arow[1] + bj;
      #pragma unroll
      for (int c = 0; c < CIN; ++c) {
        c0 = fmaf(kf[c], sv[c], c0);
        c1 = fmaf(kf[CIN+c], sv[c], c1);
      }
      if (j == 0) {
        float acc = (s == 0) ? 0.f : bndUp;
        acc += c0; rowD[0] = acc;
        acc += c1; rowD[1] = acc;
      } else {
        float left = rowD[0];
        float D0;
        if (s == 0) {
          D0 = c0 + left;                         // global row 0: left-only
        } else {
          D0 = c0 + fminf(bndDg, fminf(bndUp, left));
        }
        float lD = rowD[1];
        float D1 = c1 + fminf(left, fminf(D0, lD));  // diag=left, up=D0
        rowD[0] = D0; rowD[1] = D1;
      }
      nb = rowD[1];
    }
    // boundary hand-off to the next strip (within-wave, offset 8)
    float rD = __shfl_up(nb, 8u);
    bndDg = bndUp;
    bndUp = rD;
  }

  if (s == NSTRIP-1) feat_lds[f] = rowD[1];
  __syncthreads();

  // --- MLP: 32 -> 128 relu -> 128 relu -> 10 softmax (threads 0..127) ---
  if (tid < HID) {
    float acc = b1[tid];
    #pragma unroll
    for (int k = 0; k < NF; ++k) acc = fmaf(feat_lds[k], W1[k*HID + tid], acc);
    h1_lds[tid] = fmaxf(acc, 0.f);
  }
  __syncthreads();
  if (tid < HID) {
    const float4* hh = (const float4*)h1_lds;
    float a0 = b2[tid], a1 = 0.f, a2 = 0.f, a3 = 0.f;
    #pragma unroll
    for (int k = 0; k < HID/4; ++k) {
      float4 h4 = hh[k];
      a0 = fmaf(h4.x, W2[(4*k+0)*HID + tid], a0);
      a1 = fmaf(h4.y, W2[(4*k+1)*HID + tid], a1);
      a2 = fmaf(h4.z, W2[(4*k+2)*HID + tid], a2);
      a3 = fmaf(h4.w, W2[(4*k+3)*HID + tid], a3);
    }
    h2_lds[tid] = fmaxf((a0 + a1) + (a2 + a3), 0.f);
  }
  __syncthreads();
  if (tid < NCLS) {
    const float4* hh = (const float4*)h2_lds;
    float a0 = bl[tid], a1 = 0.f, a2 = 0.f, a3 = 0.f;
    #pragma unroll
    for (int k = 0; k < HID/4; ++k) {
      float4 h4 = hh[k];
      a0 = fmaf(h4.x, Wl[(4*k+0)*NCLS + tid], a0);
      a1 = fmaf(h4.y, Wl[(4*k+1)*NCLS + tid], a1);
      a2 = fmaf(h4.z, Wl[(4*k+2)*NCLS + tid], a2);
      a3 = fmaf(h4.w, Wl[(4*k+3)*NCLS + tid], a3);
    }
    logit_lds[tid] = (a0 + a1) + (a2 + a3);
  }
  __syncthreads();
  if (tid == 0) {
    float mx = logit_lds[0];
    #pragma unroll
    for (int j = 1; j < NCLS; ++j) mx = fmaxf(mx, logit_lds[j]);
    float e[NCLS]; float sum = 0.f;
    #pragma unroll
    for (int j = 0; j < NCLS; ++j) { e[j] = __expf(logit_lds[j] - mx); sum += e[j]; }
    float inv = 1.f / sum;
    float* op = out + bid*NCLS;
    #pragma unroll
    for (int j = 0; j < NCLS; ++j) op[j] = e[j] * inv;
  }
}

extern "C" void kernel_launch(void* const* d_in, const int* in_sizes, int n_in,
                              void* d_out, int out_size, void* d_ws, size_t ws_size,
                              hipStream_t stream) {
  const float* x    = (const float*)d_in[0];
  const float* kern = (const float*)d_in[1];
  const float* W1   = (const float*)d_in[2];
  const float* b1   = (const float*)d_in[3];
  const float* W2   = (const float*)d_in[4];
  const float* b2   = (const float*)d_in[5];
  const float* Wl   = (const float*)d_in[6];
  const float* bl   = (const float*)d_in[7];
  float* out = (float*)d_out;

  dtwnet_fused<<<2048, 256, 0, stream>>>(x, kern, W1, b1, W2, b2, Wl, bl, out);
}

// Round 8
// 84.917 us; speedup vs baseline: 1.0350x; 1.0350x over previous
//
#include <hip/hip_runtime.h>

#define NT   24
#define CIN  9
#define NF   32
#define KM   16
#define HID  128
#define NCLS 10
#define SEQ_LEN (NT*CIN)   // 216
#define PADJ 12            // seq LDS row pitch (floats), 16B-aligned columns
#define NSTRIP 4           // 4 strips of 4 rows; pipelined via shfl

typedef float vf2 __attribute__((ext_vector_type(2)));

// D[m-1,n-1] (forward DTW) == backtracked path-cost sum (telescoping).
// Cost via quadratic expansion with kf pre-scaled by -2, PACKED over row
// pairs with v_pk_fma_f32 (__builtin_elementwise_fma on float2): per step
// 18 packed fma for 4 rows instead of 36 scalar.
//
// Block = 256 threads = 4 waves, 2 sequences. Waves 0,1 -> seq 0;
// waves 2,3 -> seq 1. Within a seq: f = (wave&1)*16 + (lane&15),
// strip s = lane>>4 computes rows [4s,4s+4), skewed (step t -> column
// t-s); boundary D flows strip s -> s+1 via __shfl_up(.,16).
// MLP shares weight loads across the 2 sequences (one load, 2 fma).
__global__ __launch_bounds__(256, 4) void dtwnet_fused(
    const float* __restrict__ x,
    const float* __restrict__ kern,
    const float* __restrict__ W1, const float* __restrict__ b1,
    const float* __restrict__ W2, const float* __restrict__ b2,
    const float* __restrict__ Wl, const float* __restrict__ bl,
    float* __restrict__ out)
{
  __shared__ float seq_lds[2*NT*PADJ];
  __shared__ float bcol[2*32];            // ||x_j||^2 per column (padded)
  __shared__ float feat_lds[2*NF];
  __shared__ float h1_lds[2*HID];
  __shared__ float h2_lds[2*HID];
  __shared__ float logit_lds[2*NCLS];

  const int tid  = threadIdx.x;
  const int bid  = blockIdx.x;
  const int wave = tid >> 6;
  const int lane = tid & 63;
  const int seqi = wave >> 1;             // 0 or 1
  const int s    = lane >> 4;             // strip 0..3
  const int f_lo = lane & 15;
  const int f    = (wave & 1)*16 + f_lo;  // filter 0..31

  // filter strip (4 rows x 9 ch) from global (18 KB, L2-hot), pre-barrier
  float kraw[4*CIN];
  {
    const float4* kp = (const float4*)(kern + f*(KM*CIN) + s*(4*CIN));
    float4 t0=kp[0], t1=kp[1], t2=kp[2], t3=kp[3], t4=kp[4],
           t5=kp[5], t6=kp[6], t7=kp[7], t8=kp[8];
    kraw[0]=t0.x; kraw[1]=t0.y; kraw[2]=t0.z; kraw[3]=t0.w;
    kraw[4]=t1.x; kraw[5]=t1.y; kraw[6]=t1.z; kraw[7]=t1.w;
    kraw[8]=t2.x; kraw[9]=t2.y; kraw[10]=t2.z; kraw[11]=t2.w;
    kraw[12]=t3.x; kraw[13]=t3.y; kraw[14]=t3.z; kraw[15]=t3.w;
    kraw[16]=t4.x; kraw[17]=t4.y; kraw[18]=t4.z; kraw[19]=t4.w;
    kraw[20]=t5.x; kraw[21]=t5.y; kraw[22]=t5.z; kraw[23]=t5.w;
    kraw[24]=t6.x; kraw[25]=t6.y; kraw[26]=t6.z; kraw[27]=t6.w;
    kraw[28]=t7.x; kraw[29]=t7.y; kraw[30]=t7.z; kraw[31]=t7.w;
    kraw[32]=t8.x; kraw[33]=t8.y; kraw[34]=t8.z; kraw[35]=t8.w;
  }

  // stage 2 sequences (432 floats), padded to 12/timestep
  for (int d = tid; d < 2*SEQ_LEN; d += 256) {
    int sq = d / SEQ_LEN;
    int r  = d - sq*SEQ_LEN;
    int jj = r / CIN, cc = r - jj*CIN;
    seq_lds[sq*NT*PADJ + jj*PADJ + cc] = x[bid*(2*SEQ_LEN) + d];
  }
  __syncthreads();

  // column norms ||x_j||^2 for both seqs
  {
    int sq = tid >> 5, j = tid & 31;
    if (sq < 2 && j < NT) {
      const float4* sp = (const float4*)(seq_lds + sq*NT*PADJ + j*PADJ);
      float4 q0 = sp[0], q1 = sp[1], q2 = sp[2];
      bcol[sq*32 + j] = q0.x*q0.x + q0.y*q0.y + q0.z*q0.z + q0.w*q0.w
                      + q1.x*q1.x + q1.y*q1.y + q1.z*q1.z + q1.w*q1.w
                      + q2.x*q2.x;
    }
  }

  // pack rows (0,1) and (2,3): kf01/kf23, norms, then pre-scale by -2
  vf2 kf01[CIN], kf23[CIN], ar01 = {0.f,0.f}, ar23 = {0.f,0.f};
  #pragma unroll
  for (int c = 0; c < CIN; ++c) {
    vf2 a = {kraw[c],        kraw[CIN+c]};
    vf2 b = {kraw[2*CIN+c],  kraw[3*CIN+c]};
    ar01 = __builtin_elementwise_fma(a, a, ar01);
    ar23 = __builtin_elementwise_fma(b, b, ar23);
    kf01[c] = a * (-2.f);
    kf23[c] = b * (-2.f);
  }
  __syncthreads();

  const float* sl = seq_lds + seqi*NT*PADJ;
  const float* bc = bcol + seqi*32;

  float rowD[4];
  float bndUp = 0.f, bndDg = 0.f;

  #pragma unroll 1
  for (int t = 0; t < NT + NSTRIP - 1; ++t) {   // 27 steps
    int j = t - s;
    bool active = (j >= 0) && (j < NT);
    float nb = 0.f;
    if (active) {
      const float4* sp = (const float4*)(sl + j*PADJ);
      float4 q0 = sp[0], q1 = sp[1], q2 = sp[2];
      float bj = bc[j];
      float sv[CIN] = {q0.x,q0.y,q0.z,q0.w,q1.x,q1.y,q1.z,q1.w,q2.x};
      vf2 c01 = ar01 + bj;
      vf2 c23 = ar23 + bj;
      #pragma unroll
      for (int c = 0; c < CIN; ++c) {
        vf2 sc = {sv[c], sv[c]};
        c01 = __builtin_elementwise_fma(kf01[c], sc, c01);
        c23 = __builtin_elementwise_fma(kf23[c], sc, c23);
      }
      float cost[4] = {c01.x, c01.y, c23.x, c23.y};
      if (j == 0) {
        float acc = (s == 0) ? 0.f : bndUp;
        #pragma unroll
        for (int r = 0; r < 4; ++r) { acc += cost[r]; rowD[r] = acc; }
      } else {
        float left = rowD[0];
        float D0;
        if (s == 0) {
          D0 = cost[0] + left;                    // global row 0: left-only
        } else {
          D0 = cost[0] + fminf(bndDg, fminf(bndUp, left));
        }
        float diag = left, up = D0;
        rowD[0] = D0;
        #pragma unroll
        for (int r = 1; r < 4; ++r) {
          float lD = rowD[r];
          float D2 = cost[r] + fminf(diag, fminf(up, lD));
          diag = lD;
          rowD[r] = D2; up = D2;
        }
      }
      nb = rowD[3];
    }
    float rD = __shfl_up(nb, 16u);
    bndDg = bndUp;
    bndUp = rD;
  }

  if (s == NSTRIP-1) feat_lds[seqi*NF + f] = rowD[3];
  __syncthreads();

  // --- MLP, weight loads shared across the 2 sequences (threads 0..127) ---
  if (tid < HID) {
    const float* f0 = feat_lds;
    const float* f1 = feat_lds + NF;
    float a0 = b1[tid], a1 = a0;
    #pragma unroll
    for (int k = 0; k < NF; ++k) {
      float w = W1[k*HID + tid];
      a0 = fmaf(f0[k], w, a0);
      a1 = fmaf(f1[k], w, a1);
    }
    h1_lds[tid]       = fmaxf(a0, 0.f);
    h1_lds[HID + tid] = fmaxf(a1, 0.f);
  }
  __syncthreads();
  if (tid < HID) {
    const float4* h0 = (const float4*)h1_lds;
    const float4* h1v = (const float4*)(h1_lds + HID);
    float p0 = b2[tid], p1 = 0.f, p2 = 0.f, p3 = 0.f;
    float q0 = b2[tid], q1 = 0.f, q2 = 0.f, q3 = 0.f;
    #pragma unroll
    for (int k = 0; k < HID/4; ++k) {
      float w0 = W2[(4*k+0)*HID + tid];
      float w1 = W2[(4*k+1)*HID + tid];
      float w2 = W2[(4*k+2)*HID + tid];
      float w3 = W2[(4*k+3)*HID + tid];
      float4 ha = h0[k], hb = h1v[k];
      p0 = fmaf(ha.x, w0, p0); p1 = fmaf(ha.y, w1, p1);
      p2 = fmaf(ha.z, w2, p2); p3 = fmaf(ha.w, w3, p3);
      q0 = fmaf(hb.x, w0, q0); q1 = fmaf(hb.y, w1, q1);
      q2 = fmaf(hb.z, w2, q2); q3 = fmaf(hb.w, w3, q3);
    }
    h2_lds[tid]       = fmaxf((p0 + p1) + (p2 + p3), 0.f);
    h2_lds[HID + tid] = fmaxf((q0 + q1) + (q2 + q3), 0.f);
  }
  __syncthreads();
  if (tid < NCLS) {
    const float4* h0 = (const float4*)h2_lds;
    const float4* h1v = (const float4*)(h2_lds + HID);
    float p0 = bl[tid], p1 = 0.f, p2 = 0.f, p3 = 0.f;
    float q0 = bl[tid], q1 = 0.f, q2 = 0.f, q3 = 0.f;
    #pragma unroll
    for (int k = 0; k < HID/4; ++k) {
      float w0 = Wl[(4*k+0)*NCLS + tid];
      float w1 = Wl[(4*k+1)*NCLS + tid];
      float w2 = Wl[(4*k+2)*NCLS + tid];
      float w3 = Wl[(4*k+3)*NCLS + tid];
      float4 ha = h0[k], hb = h1v[k];
      p0 = fmaf(ha.x, w0, p0); p1 = fmaf(ha.y, w1, p1);
      p2 = fmaf(ha.z, w2, p2); p3 = fmaf(ha.w, w3, p3);
      q0 = fmaf(hb.x, w0, q0); q1 = fmaf(hb.y, w1, q1);
      q2 = fmaf(hb.z, w2, q2); q3 = fmaf(hb.w, w3, q3);
    }
    logit_lds[tid]        = (p0 + p1) + (p2 + p3);
    logit_lds[NCLS + tid] = (q0 + q1) + (q2 + q3);
  }
  __syncthreads();
  if (tid < 2) {
    const float* lg = &logit_lds[tid*NCLS];
    float mx = lg[0];
    #pragma unroll
    for (int j = 1; j < NCLS; ++j) mx = fmaxf(mx, lg[j]);
    float e[NCLS]; float sum = 0.f;
    #pragma unroll
    for (int j = 0; j < NCLS; ++j) { e[j] = __expf(lg[j] - mx); sum += e[j]; }
    float inv = 1.f / sum;
    float* op = out + (bid*2 + tid)*NCLS;
    #pragma unroll
    for (int j = 0; j < NCLS; ++j) op[j] = e[j] * inv;
  }
}

extern "C" void kernel_launch(void* const* d_in, const int* in_sizes, int n_in,
                              void* d_out, int out_size, void* d_ws, size_t ws_size,
                              hipStream_t stream) {
  const float* x    = (const float*)d_in[0];
  const float* kern = (const float*)d_in[1];
  const float* W1   = (const float*)d_in[2];
  const float* b1   = (const float*)d_in[3];
  const float* W2   = (const float*)d_in[4];
  const float* b2   = (const float*)d_in[5];
  const float* Wl   = (const float*)d_in[6];
  const float* bl   = (const float*)d_in[7];
  float* out = (float*)d_out;

  dtwnet_fused<<<1024, 256, 0, stream>>>(x, kern, W1, b1, W2, b2, Wl, bl, out);
}